// Round 4
// baseline (254.921 us; speedup 1.0000x reference)
//
#include <hip/hip_runtime.h>

#define LOG2E 1.4426950408889634f

typedef __bf16 bf16x8 __attribute__((ext_vector_type(8)));
typedef short s16x4 __attribute__((ext_vector_type(4)));
typedef float f32x4 __attribute__((ext_vector_type(4)));

#define BB 2
#define NN 2048
#define CC 384
#define NH 12
#define HD 32
#define MROWS (BB * NN)   /* 4096 */

__device__ __forceinline__ unsigned short f2bf(float f) {
  __bf16 h = (__bf16)f;
  return __builtin_bit_cast(unsigned short, h);
}

__device__ __forceinline__ bf16x8 ldg_bf8(const unsigned short* p) {
  uint4 v = *reinterpret_cast<const uint4*>(p);
  return __builtin_bit_cast(bf16x8, v);
}

__device__ __forceinline__ s16x4 ldg_bf4(const unsigned short* p) {
  uint2 v = *reinterpret_cast<const uint2*>(p);
  return __builtin_bit_cast(s16x4, v);
}

// K=16 bf16 MFMA: 16x16x16 (A,B = 4 bf16/lane; lane(c,quad): A[m=c][k=quad*4+j],
// B[k=quad*4+j][n=c]; C/D: row=quad*4+r, col=c)
__device__ __forceinline__ f32x4 mfma16(s16x4 a, s16x4 b, f32x4 c) {
#if __has_builtin(__builtin_amdgcn_mfma_f32_16x16x16bf16_1k)
  return __builtin_amdgcn_mfma_f32_16x16x16bf16_1k(a, b, c, 0, 0, 0);
#elif __has_builtin(__builtin_amdgcn_mfma_f32_16x16x16_bf16)
  return __builtin_amdgcn_mfma_f32_16x16x16_bf16(a, b, c, 0, 0, 0);
#else
  asm volatile("v_mfma_f32_16x16x16_bf16 %0, %1, %2, %0"
               : "+v"(c) : "v"(a), "v"(b));
  return c;
#endif
}

// ---------------- prep: weights fp32->bf16 only ------------------------------
__global__ __launch_bounds__(256) void prep_w_kernel(
    const float* __restrict__ q_w, const float* __restrict__ kv_w,
    const float* __restrict__ proj_w, unsigned short* __restrict__ qwb,
    unsigned short* __restrict__ kvwb, unsigned short* __restrict__ pwb) {
  int i = blockIdx.x * 256 + threadIdx.x;
  if (i < 147456) { qwb[i] = f2bf(q_w[i]); return; }
  i -= 147456;
  if (i < 294912) { kvwb[i] = f2bf(kv_w[i]); return; }
  i -= 294912;
  pwb[i] = f2bf(proj_w[i]);
}

// ------- fused QKV GEMM + l2norm + layout: Qs,Kn=(b,h,n,d), VT=(b,h,d,n) -----
// Grid (64, NH). Wave = 16 rows x 96 cols (q|k|v 32-col slices of head h).
// A (x) is cast fp32->bf16 inline.
__global__ __launch_bounds__(256, 3) void gemm_qkv_norm_kernel(
    const float* __restrict__ x, const unsigned short* __restrict__ qwb,
    const unsigned short* __restrict__ kvwb, const float* __restrict__ q_b,
    const float* __restrict__ kv_b, const float* __restrict__ qe,
    const float* __restrict__ temperature, unsigned short* __restrict__ Qs,
    unsigned short* __restrict__ Kn, unsigned short* __restrict__ VT) {
  int wave = threadIdx.x >> 6;
  int lane = threadIdx.x & 63;
  int c = lane & 15, quad = lane >> 4;
  int h = blockIdx.y;
  int m0 = blockIdx.x * 64 + wave * 16;
  const float* arow = x + (long)(m0 + c) * CC + quad * 8;
  const unsigned short* brow[6];
  brow[0] = qwb + (long)(h * 32 + c) * CC + quad * 8;
  brow[1] = qwb + (long)(h * 32 + 16 + c) * CC + quad * 8;
  brow[2] = kvwb + (long)(h * 32 + c) * CC + quad * 8;
  brow[3] = kvwb + (long)(h * 32 + 16 + c) * CC + quad * 8;
  brow[4] = kvwb + (long)(CC + h * 32 + c) * CC + quad * 8;
  brow[5] = kvwb + (long)(CC + h * 32 + 16 + c) * CC + quad * 8;

  auto lda = [&](int kk) -> bf16x8 {
    f32x4 fa = *reinterpret_cast<const f32x4*>(arow + kk);
    f32x4 fb = *reinterpret_cast<const f32x4*>(arow + kk + 4);
    bf16x8 r = {(__bf16)fa[0], (__bf16)fa[1], (__bf16)fa[2], (__bf16)fa[3],
                (__bf16)fb[0], (__bf16)fb[1], (__bf16)fb[2], (__bf16)fb[3]};
    return r;
  };

  f32x4 acc[6] = {};
  bf16x8 ac = lda(0);
  bf16x8 bc[6];
#pragma unroll
  for (int t = 0; t < 6; ++t) bc[t] = ldg_bf8(brow[t]);
  for (int kk = 0; kk < CC; kk += 32) {
    bf16x8 an;
    bf16x8 bn[6];
    if (kk + 32 < CC) {
      an = lda(kk + 32);
#pragma unroll
      for (int t = 0; t < 6; ++t) bn[t] = ldg_bf8(brow[t] + kk + 32);
    }
#pragma unroll
    for (int t = 0; t < 6; ++t)
      acc[t] = __builtin_amdgcn_mfma_f32_16x16x32_bf16(ac, bc[t], acc[t], 0, 0, 0);
    ac = an;
#pragma unroll
    for (int t = 0; t < 6; ++t) bc[t] = bn[t];
  }

  // epilogue: bias + l2norm(q,k) + qe/scale + stores
  float qb0 = q_b[h * 32 + c], qb1 = q_b[h * 32 + 16 + c];
  float kb0 = kv_b[h * 32 + c], kb1 = kv_b[h * 32 + 16 + c];
  float vb0 = kv_b[CC + h * 32 + c], vb1 = kv_b[CC + h * 32 + 16 + c];
  float qe0 = qe[h * HD + c], qe1 = qe[h * HD + 16 + c];
  // softplus(t) * ln(N) * log2(e) = softplus(t) * 11
  float sc = log1pf(expf(temperature[h])) * 11.0f;
  int b = m0 >> 11;
  int nb = (m0 & 2047) + quad * 4;
  int pair = b * NH + h;
  unsigned short* qsb = Qs + ((long)pair * NN + nb) * HD;
  unsigned short* knb = Kn + ((long)pair * NN + nb) * HD;
  ushort4 vp0, vp1;
#pragma unroll
  for (int r = 0; r < 4; ++r) {
    float q0 = acc[0][r] + qb0, q1 = acc[1][r] + qb1;
    float k0 = acc[2][r] + kb0, k1 = acc[3][r] + kb1;
    float v0 = acc[4][r] + vb0, v1 = acc[5][r] + vb1;
    float qs = q0 * q0 + q1 * q1, ks = k0 * k0 + k1 * k1;
#pragma unroll
    for (int off = 8; off; off >>= 1) {
      qs += __shfl_xor(qs, off);
      ks += __shfl_xor(ks, off);
    }
    float qi = 1.0f / fmaxf(sqrtf(qs), 1e-12f);
    float ki = 1.0f / fmaxf(sqrtf(ks), 1e-12f);
    qsb[r * HD + c] = f2bf((q0 * qi + qe0) * sc);
    qsb[r * HD + 16 + c] = f2bf((q1 * qi + qe1) * sc);
    knb[r * HD + c] = f2bf(k0 * ki);
    knb[r * HD + 16 + c] = f2bf(k1 * ki);
    ((unsigned short*)&vp0)[r] = f2bf(v0);
    ((unsigned short*)&vp1)[r] = f2bf(v1);
  }
  *reinterpret_cast<ushort4*>(VT + ((long)pair * HD + c) * NN + nb) = vp0;
  *reinterpret_cast<ushort4*>(VT + ((long)pair * HD + 16 + c) * NN + nb) = vp1;
}

// -------- attention: S^T formulation, no LDS, K-split x2 partials ------------
// Per 64-K chunk: 4x QK^T (16x16x32, S^T) -> exp2 -> pack -> 8x PV (16x16x16).
__global__ __launch_bounds__(256, 4) void attn_kernel(
    const unsigned short* __restrict__ Qs, const unsigned short* __restrict__ Kn,
    const unsigned short* __restrict__ VT, const float* __restrict__ pos_bias,
    float* __restrict__ Opart, float* __restrict__ Lpart) {
  int wave = threadIdx.x >> 6;
  int lane = threadIdx.x & 63;
  int c = lane & 15, quad = lane >> 4;
  int pair = blockIdx.y;  // b*NH + h
  int h = pair % NH;
  int qt = blockIdx.x >> 1, ks = blockIdx.x & 1;
  const unsigned short* Qp = Qs + (long)pair * NN * HD;
  const unsigned short* Kp = Kn + (long)pair * NN * HD;
  const unsigned short* Vp = VT + (long)pair * HD * NN;
  const float* bp = pos_bias + h * NN;
  int q0 = qt * 64 + wave * 16;
  int kbase = ks << 10, kend = kbase + 1024;

  // Q fragment: B-operand of S^T MFMA (B[k=d][n=q]); same load as A of S.
  bf16x8 qf = ldg_bf8(Qp + (long)(q0 + c) * HD + quad * 8);
  f32x4 o0 = {}, o1 = {};  // O^T[d][q]: d=quad*4+r(+16), q=c
  float rs = 0.f;          // all of this lane's p belong to q=c

  bf16x8 kfa[4], kfb[4];
  f32x4 bba[4], bbb[4];

  auto loadkb = [&](bf16x8(&kf)[4], f32x4(&bb)[4], int k0) {
#pragma unroll
    for (int t = 0; t < 4; ++t) {
      kf[t] = ldg_bf8(Kp + (long)(k0 + t * 16 + c) * HD + quad * 8);
      bb[t] = *reinterpret_cast<const f32x4*>(bp + k0 + t * 16 + quad * 4);
    }
  };

  auto compute = [&](const bf16x8(&kf)[4], const f32x4(&bb)[4], int k0) {
    // V A-fragments (issued first; consumed after softmax)
    s16x4 vlo[4], vhi[4];
#pragma unroll
    for (int t = 0; t < 4; ++t) {
      vlo[t] = ldg_bf4(Vp + (long)c * NN + k0 + t * 16 + quad * 4);
      vhi[t] = ldg_bf4(Vp + (long)(c + 16) * NN + k0 + t * 16 + quad * 4);
    }
    f32x4 s[4];
#pragma unroll
    for (int t = 0; t < 4; ++t) {
      f32x4 z = {};
      s[t] = __builtin_amdgcn_mfma_f32_16x16x32_bf16(kf[t], qf, z, 0, 0, 0);
    }
    s16x4 pf[4];
#pragma unroll
    for (int t = 0; t < 4; ++t) {
      float p0 = exp2f(fmaf(bb[t][0], LOG2E, s[t][0]));
      float p1 = exp2f(fmaf(bb[t][1], LOG2E, s[t][1]));
      float p2 = exp2f(fmaf(bb[t][2], LOG2E, s[t][2]));
      float p3 = exp2f(fmaf(bb[t][3], LOG2E, s[t][3]));
      rs += (p0 + p1) + (p2 + p3);
      pf[t] = (s16x4){(short)f2bf(p0), (short)f2bf(p1),
                      (short)f2bf(p2), (short)f2bf(p3)};
    }
#pragma unroll
    for (int t = 0; t < 4; ++t) {
      o0 = mfma16(vlo[t], pf[t], o0);
      o1 = mfma16(vhi[t], pf[t], o1);
    }
  };

  loadkb(kfa, bba, kbase);
#pragma unroll 1
  for (int k0 = kbase; k0 < kend; k0 += 128) {
    loadkb(kfb, bbb, k0 + 64);
    compute(kfa, bba, k0);
    if (k0 + 128 < kend) loadkb(kfa, bba, k0 + 128);
    compute(kfb, bbb, k0 + 64);
  }

  rs += __shfl_xor(rs, 16);
  rs += __shfl_xor(rs, 32);
  float* op = Opart + ((long)(ks * 24 + pair) * NN + q0 + c) * HD + quad * 4;
  *reinterpret_cast<f32x4*>(op) = o0;
  *reinterpret_cast<f32x4*>(op + 16) = o1;
  if (lane < 16) Lpart[(long)(ks * 24 + pair) * NN + q0 + c] = rs;
}

// ---------------- combine K-split partials -> ao (bf16, (b,n,h,d)) ----------
__global__ __launch_bounds__(256) void combine_kernel(
    const float* __restrict__ Opart, const float* __restrict__ Lpart,
    unsigned short* __restrict__ ao) {
  const long PS = 24L * NN * HD;
  int idx = blockIdx.x * 256 + threadIdx.x;  // 24*2048*8
  int pair = idx / (NN * 8);
  int rem = idx % (NN * 8);
  int q = rem >> 3, d4 = rem & 7;
  long o = ((long)pair * NN + q) * HD + d4 * 4;
  f32x4 a = *reinterpret_cast<const f32x4*>(Opart + o);
  f32x4 b = *reinterpret_cast<const f32x4*>(Opart + PS + o);
  float l = Lpart[(long)pair * NN + q] + Lpart[24L * NN + (long)pair * NN + q];
  float inv = 1.0f / l;
  int h = pair % NH, bb = pair / NH;
  ushort4 st;
  st.x = f2bf((a[0] + b[0]) * inv);
  st.y = f2bf((a[1] + b[1]) * inv);
  st.z = f2bf((a[2] + b[2]) * inv);
  st.w = f2bf((a[3] + b[3]) * inv);
  *reinterpret_cast<ushort4*>(ao + ((long)bb * NN + q) * CC + h * HD + d4 * 4) = st;
}

// ---------------- proj: out = attn_out @ proj_w^T + proj_b (fp32 out) --------
__global__ __launch_bounds__(256) void proj_kernel(
    const unsigned short* __restrict__ ab, const unsigned short* __restrict__ pwb,
    const float* __restrict__ proj_b, float* __restrict__ out) {
  int wave = threadIdx.x >> 6;
  int lane = threadIdx.x & 63;
  int c = lane & 15, quad = lane >> 4;
  int m0 = blockIdx.x * 64 + wave * 16;
  int n0 = blockIdx.y * 64;
  const unsigned short* arow = ab + (long)(m0 + c) * CC + quad * 8;
  const unsigned short* brow[4];
#pragma unroll
  for (int t = 0; t < 4; ++t)
    brow[t] = pwb + (long)(n0 + t * 16 + c) * CC + quad * 8;
  f32x4 acc[4] = {};
  bf16x8 ac = ldg_bf8(arow);
  bf16x8 bc[4];
#pragma unroll
  for (int t = 0; t < 4; ++t) bc[t] = ldg_bf8(brow[t]);
  for (int kk = 0; kk < CC; kk += 32) {
    bf16x8 an;
    bf16x8 bn[4];
    if (kk + 32 < CC) {
      an = ldg_bf8(arow + kk + 32);
#pragma unroll
      for (int t = 0; t < 4; ++t) bn[t] = ldg_bf8(brow[t] + kk + 32);
    }
#pragma unroll
    for (int t = 0; t < 4; ++t)
      acc[t] = __builtin_amdgcn_mfma_f32_16x16x32_bf16(ac, bc[t], acc[t], 0, 0, 0);
    ac = an;
#pragma unroll
    for (int t = 0; t < 4; ++t) bc[t] = bn[t];
  }
#pragma unroll
  for (int t = 0; t < 4; ++t) {
    int o = n0 + t * 16 + c;
    float bv = proj_b[o];
#pragma unroll
    for (int r = 0; r < 4; ++r) {
      out[(long)(m0 + quad * 4 + r) * CC + o] = acc[t][r] + bv;
    }
  }
}

extern "C" void kernel_launch(void* const* d_in, const int* in_sizes, int n_in,
                              void* d_out, int out_size, void* d_ws, size_t ws_size,
                              hipStream_t stream) {
  const float* x = (const float*)d_in[0];
  const float* q_w = (const float*)d_in[1];
  const float* q_b = (const float*)d_in[2];
  const float* kv_w = (const float*)d_in[3];
  const float* kv_b = (const float*)d_in[4];
  const float* qe = (const float*)d_in[5];
  const float* temp = (const float*)d_in[6];
  const float* pos_bias = (const float*)d_in[7];
  const float* proj_w = (const float*)d_in[8];
  const float* proj_b = (const float*)d_in[9];
  float* out = (float*)d_out;

  char* ws = (char*)d_ws;
  unsigned short* qwb = (unsigned short*)(ws + 0);         //   294,912 B
  unsigned short* kvwb = (unsigned short*)(ws + 294912);   //   589,824 B
  unsigned short* pwb = (unsigned short*)(ws + 884736);    //   294,912 B
  unsigned short* Qs = (unsigned short*)(ws + 1179648);    // 3,145,728 B
  unsigned short* Kn = (unsigned short*)(ws + 4325376);    // 3,145,728 B
  unsigned short* VT = (unsigned short*)(ws + 7471104);    // 3,145,728 B
  unsigned short* ao = (unsigned short*)(ws + 10616832);   // 3,145,728 B
  float* Opart = (float*)(ws + 13762560);                  // 12,582,912 B
  float* Lpart = (float*)(ws + 26345472);                  //   393,216 B -> 26.7 MB

  prep_w_kernel<<<2304, 256, 0, stream>>>(q_w, kv_w, proj_w, qwb, kvwb, pwb);
  gemm_qkv_norm_kernel<<<dim3(64, NH), 256, 0, stream>>>(x, qwb, kvwb, q_b, kv_b,
                                                         qe, temp, Qs, Kn, VT);
  attn_kernel<<<dim3(64, 24), 256, 0, stream>>>(Qs, Kn, VT, pos_bias, Opart, Lpart);
  combine_kernel<<<1536, 256, 0, stream>>>(Opart, Lpart, ao);
  proj_kernel<<<dim3(64, 6), 256, 0, stream>>>(ao, pwb, proj_b, out);
}

// Round 6
// 147.302 us; speedup vs baseline: 1.7306x; 1.7306x over previous
//
#include <hip/hip_runtime.h>

#define LOG2E 1.4426950408889634f

typedef __bf16 bf16x8 __attribute__((ext_vector_type(8)));
typedef short s16x4 __attribute__((ext_vector_type(4)));
typedef float f32x4 __attribute__((ext_vector_type(4)));

#define BB 2
#define NN 2048
#define CC 384
#define NH 12
#define HD 32
#define MROWS (BB * NN)   /* 4096 */

__device__ __forceinline__ unsigned short f2bf(float f) {
  __bf16 h = (__bf16)f;
  return __builtin_bit_cast(unsigned short, h);
}

__device__ __forceinline__ bf16x8 ldg_bf8(const unsigned short* p) {
  uint4 v = *reinterpret_cast<const uint4*>(p);
  return __builtin_bit_cast(bf16x8, v);
}

// async global->LDS DMA, 16B per lane; LDS dest = wave-uniform base + lane*16
typedef __attribute__((address_space(1))) const void gas_void;
typedef __attribute__((address_space(3))) void las_void;
__device__ __forceinline__ void gload_lds16(const void* g, void* l) {
  __builtin_amdgcn_global_load_lds((gas_void*)(unsigned long long)g,
                                   (las_void*)(unsigned long long)l, 16, 0, 0);
}

__device__ __forceinline__ f32x4 mfma32(bf16x8 a, bf16x8 b, f32x4 c) {
  return __builtin_amdgcn_mfma_f32_16x16x32_bf16(a, b, c, 0, 0, 0);
}

// 16x16x16 bf16 MFMA (A,B = 4 bf16/lane: X[m|n=lane&15][k=(lane>>4)*4+j];
// C/D: row=(lane>>4)*4+r, col=lane&15). Host pass must not see the builtin.
__device__ __forceinline__ f32x4 mfma16(s16x4 a, s16x4 b, f32x4 c) {
#if defined(__HIP_DEVICE_COMPILE__)
#if __has_builtin(__builtin_amdgcn_mfma_f32_16x16x16bf16_1k)
  return __builtin_amdgcn_mfma_f32_16x16x16bf16_1k(a, b, c, 0, 0, 0);
#else
  asm volatile("v_mfma_f32_16x16x16_bf16 %0, %1, %2, %0"
               : "+v"(c) : "v"(a), "v"(b));
  return c;
#endif
#else
  return c;  // host type-check stub
#endif
}

// ---------------- prep: fp32->bf16 casts (x + 3 weight matrices) -------------
__global__ __launch_bounds__(256) void prep_kernel(
    const float* __restrict__ x, const float* __restrict__ q_w,
    const float* __restrict__ kv_w, const float* __restrict__ proj_w,
    unsigned short* __restrict__ xb, unsigned short* __restrict__ qwb,
    unsigned short* __restrict__ kvwb, unsigned short* __restrict__ pwb) {
  int i = blockIdx.x * 256 + threadIdx.x;
  if (i < 1572864) { xb[i] = f2bf(x[i]); return; }
  i -= 1572864;
  if (i < 147456) { qwb[i] = f2bf(q_w[i]); return; }
  i -= 147456;
  if (i < 294912) { kvwb[i] = f2bf(kv_w[i]); return; }
  i -= 294912;
  pwb[i] = f2bf(proj_w[i]);
}

// ------- fused QKV GEMM + l2norm, LDS-staged (m97 structure) -----------------
// Grid (64, NH). Block tile 64M x 96N (head h: q|k|v 32-col slices), BK=64.
// LDS per buf: A 64x64 bf16 (8KB) + B 96x64 bf16 (12KB) = 20KB; double = 40KB.
__global__ __launch_bounds__(256, 4) void gemm_qkv_norm_kernel(
    const unsigned short* __restrict__ xb, const unsigned short* __restrict__ qwb,
    const unsigned short* __restrict__ kvwb, const float* __restrict__ q_b,
    const float* __restrict__ kv_b, const float* __restrict__ qe,
    const float* __restrict__ temperature, unsigned short* __restrict__ Qs,
    unsigned short* __restrict__ Kn, unsigned short* __restrict__ VT) {
  __shared__ alignas(16) char smem[2][20480];
  int wave = threadIdx.x >> 6, lane = threadIdx.x & 63;
  int c = lane & 15, quad = lane >> 4;
  int h = blockIdx.y;
  int m0b = blockIdx.x * 64;
  int cid = wave * 64 + lane;

  auto stage = [&](int buf, int kk) {
    char* base = smem[buf];
#pragma unroll
    for (int j = 0; j < 2; ++j) {  // A: 512 chunks (64 rows x 128B)
      int chunk = j * 256 + cid;
      int row = chunk >> 3, e = chunk & 7;
      gload_lds16(xb + (long)(m0b + row) * CC + kk + e * 8,
                  base + j * 4096 + wave * 1024);
    }
#pragma unroll
    for (int j = 0; j < 3; ++j) {  // B: 768 chunks (96 rows x 128B)
      int chunk = j * 256 + cid;
      int row = chunk >> 3, e = chunk & 7;
      const unsigned short* src;
      if (row < 32)      src = qwb + (long)(h * 32 + row) * CC;
      else if (row < 64) src = kvwb + (long)(h * 32 + (row - 32)) * CC;
      else               src = kvwb + (long)(CC + h * 32 + (row - 64)) * CC;
      gload_lds16(src + kk + e * 8, base + 8192 + j * 4096 + wave * 1024);
    }
  };

  f32x4 acc[6] = {};
  auto compute = [&](int buf) {
    const char* base = smem[buf];
#pragma unroll
    for (int kh = 0; kh < 2; ++kh) {
      bf16x8 a = *(const bf16x8*)(base + (wave * 16 + c) * 128 + kh * 64 + quad * 16);
#pragma unroll
      for (int t = 0; t < 6; ++t) {
        bf16x8 b = *(const bf16x8*)(base + 8192 + (t * 16 + c) * 128 + kh * 64 + quad * 16);
        acc[t] = mfma32(a, b, acc[t]);
      }
    }
  };

  stage(0, 0);
#pragma unroll 1
  for (int s = 0; s < 6; ++s) {
    __syncthreads();
    if (s < 5) stage((s + 1) & 1, (s + 1) * 64);
    compute(s & 1);
  }

  // epilogue: bias + l2norm(q,k) + qe/scale + stores
  int m0 = m0b + wave * 16;
  float qb0 = q_b[h * 32 + c], qb1 = q_b[h * 32 + 16 + c];
  float kb0 = kv_b[h * 32 + c], kb1 = kv_b[h * 32 + 16 + c];
  float vb0 = kv_b[CC + h * 32 + c], vb1 = kv_b[CC + h * 32 + 16 + c];
  float qe0 = qe[h * HD + c], qe1 = qe[h * HD + 16 + c];
  float sc = log1pf(expf(temperature[h])) * 11.0f;  // softplus * log2(N)
  int b = m0 >> 11;
  int nb = (m0 & 2047) + quad * 4;
  int pair = b * NH + h;
  unsigned short* qsb = Qs + ((long)pair * NN + nb) * HD;
  unsigned short* knb = Kn + ((long)pair * NN + nb) * HD;
  ushort4 vp0, vp1;
#pragma unroll
  for (int r = 0; r < 4; ++r) {
    float q0 = acc[0][r] + qb0, q1 = acc[1][r] + qb1;
    float k0 = acc[2][r] + kb0, k1 = acc[3][r] + kb1;
    float v0 = acc[4][r] + vb0, v1 = acc[5][r] + vb1;
    float qs = q0 * q0 + q1 * q1, ks = k0 * k0 + k1 * k1;
#pragma unroll
    for (int off = 8; off; off >>= 1) {
      qs += __shfl_xor(qs, off);
      ks += __shfl_xor(ks, off);
    }
    float qi = 1.0f / fmaxf(sqrtf(qs), 1e-12f);
    float ki = 1.0f / fmaxf(sqrtf(ks), 1e-12f);
    qsb[r * HD + c] = f2bf((q0 * qi + qe0) * sc);
    qsb[r * HD + 16 + c] = f2bf((q1 * qi + qe1) * sc);
    knb[r * HD + c] = f2bf(k0 * ki);
    knb[r * HD + 16 + c] = f2bf(k1 * ki);
    ((unsigned short*)&vp0)[r] = f2bf(v0);
    ((unsigned short*)&vp1)[r] = f2bf(v1);
  }
  *reinterpret_cast<ushort4*>(VT + ((long)pair * HD + c) * NN + nb) = vp0;
  *reinterpret_cast<ushort4*>(VT + ((long)pair * HD + 16 + c) * NN + nb) = vp1;
}

// -------- attention: S^T form, LDS-staged K/V (BK=128), no K-split -----------
// Grid (32, 24). Block = 4 waves, 64 q-rows; waves share staged K/V tiles.
// LDS per buf: K 128x32 bf16 (8KB) + V^T 32x128 bf16 swizzled (8KB); dbuf 32KB.
__global__ __launch_bounds__(256, 4) void attn_kernel(
    const unsigned short* __restrict__ Qs, const unsigned short* __restrict__ Kn,
    const unsigned short* __restrict__ VT, const float* __restrict__ pos_bias,
    unsigned short* __restrict__ ao) {
  __shared__ alignas(16) char smem[2][16384];
  int wave = threadIdx.x >> 6, lane = threadIdx.x & 63;
  int c = lane & 15, quad = lane >> 4;
  int pair = blockIdx.y, h = pair % NH, b = pair / NH;
  const unsigned short* Qp = Qs + (long)pair * NN * HD;
  const unsigned short* Kp = Kn + (long)pair * NN * HD;
  const unsigned short* Vp = VT + (long)pair * HD * NN;
  const float* bp = pos_bias + h * NN;
  int q0 = blockIdx.x * 64 + wave * 16;
  bf16x8 qf = ldg_bf8(Qp + (long)(q0 + c) * HD + quad * 8);  // B-op of S^T
  f32x4 o0 = {}, o1 = {};  // O^T: d=quad*4+r (+16), q=c
  float rs = 0.f;
  int cid = wave * 64 + lane;

  auto stage = [&](int buf, int k0) {
    char* base = smem[buf];
    const char* Kg = (const char*)Kp + (long)k0 * (HD * 2);  // contiguous 8KB
    const char* Vg = (const char*)Vp + (long)k0 * 2;         // 32 rows x 256B
#pragma unroll
    for (int j = 0; j < 2; ++j) {
      int chunk = j * 256 + cid;
      gload_lds16(Kg + chunk * 16, base + j * 4096 + wave * 1024);
      int d = chunk >> 4, e = chunk & 15;
      int es = e ^ (d & 15);  // XOR-swizzled source so reads are conflict-free
      gload_lds16(Vg + (long)d * (NN * 2) + es * 16,
                  base + 8192 + j * 4096 + wave * 1024);
    }
  };

  auto compute = [&](int buf, int k0) {
    const char* kb = smem[buf];
    const char* vb = smem[buf] + 8192;
#pragma unroll
    for (int t8 = 0; t8 < 8; ++t8) {
      bf16x8 kf = *(const bf16x8*)(kb + (t8 * 16 + c) * 64 + quad * 16);
      f32x4 z = {};
      f32x4 s = mfma32(kf, qf, z);  // S^T tile: row=k (quad*4+r), col=q (c)
      f32x4 bb = *(const f32x4*)(bp + k0 + t8 * 16 + quad * 4);
      float p0 = exp2f(fmaf(bb[0], LOG2E, s[0]));
      float p1 = exp2f(fmaf(bb[1], LOG2E, s[1]));
      float p2 = exp2f(fmaf(bb[2], LOG2E, s[2]));
      float p3 = exp2f(fmaf(bb[3], LOG2E, s[3]));
      rs += (p0 + p1) + (p2 + p3);
      s16x4 pf = {(short)f2bf(p0), (short)f2bf(p1),
                  (short)f2bf(p2), (short)f2bf(p3)};
      int vsw = (((t8 * 2 + (quad >> 1)) ^ c) * 16) + (quad & 1) * 8;
      s16x4 vlo = *(const s16x4*)(vb + c * 256 + vsw);
      s16x4 vhi = *(const s16x4*)(vb + (c + 16) * 256 + vsw);
      o0 = mfma16(vlo, pf, o0);
      o1 = mfma16(vhi, pf, o1);
    }
  };

  stage(0, 0);
#pragma unroll 1
  for (int it = 0; it < 16; ++it) {
    __syncthreads();
    if (it < 15) stage((it + 1) & 1, (it + 1) * 128);
    compute(it & 1, it * 128);
  }

  rs += __shfl_xor(rs, 16);
  rs += __shfl_xor(rs, 32);
  float inv = 1.0f / rs;
  unsigned short* op = ao + (long)(b * NN + q0 + c) * CC + h * HD + quad * 4;
  ushort4 s0, s1;
#pragma unroll
  for (int r = 0; r < 4; ++r) {
    ((unsigned short*)&s0)[r] = f2bf(o0[r] * inv);
    ((unsigned short*)&s1)[r] = f2bf(o1[r] * inv);
  }
  *reinterpret_cast<ushort4*>(op) = s0;
  *reinterpret_cast<ushort4*>(op + 16) = s1;
}

// ---------------- proj: out = ao @ proj_w^T + proj_b, LDS-staged -------------
// Grid (64, 6). Block tile 64M x 64N, BK=64. LDS: (8KB+8KB)x2 = 32KB.
__global__ __launch_bounds__(256, 4) void proj_kernel(
    const unsigned short* __restrict__ ab, const unsigned short* __restrict__ pwb,
    const float* __restrict__ proj_b, float* __restrict__ out) {
  __shared__ alignas(16) char smem[2][16384];
  int wave = threadIdx.x >> 6, lane = threadIdx.x & 63;
  int c = lane & 15, quad = lane >> 4;
  int m0b = blockIdx.x * 64;
  int n0 = blockIdx.y * 64;
  int cid = wave * 64 + lane;

  auto stage = [&](int buf, int kk) {
    char* base = smem[buf];
#pragma unroll
    for (int j = 0; j < 2; ++j) {
      int chunk = j * 256 + cid;
      int row = chunk >> 3, e = chunk & 7;
      gload_lds16(ab + (long)(m0b + row) * CC + kk + e * 8,
                  base + j * 4096 + wave * 1024);
      gload_lds16(pwb + (long)(n0 + row) * CC + kk + e * 8,
                  base + 8192 + j * 4096 + wave * 1024);
    }
  };

  f32x4 acc[4] = {};
  auto compute = [&](int buf) {
    const char* base = smem[buf];
#pragma unroll
    for (int kh = 0; kh < 2; ++kh) {
      bf16x8 a = *(const bf16x8*)(base + (wave * 16 + c) * 128 + kh * 64 + quad * 16);
#pragma unroll
      for (int t = 0; t < 4; ++t) {
        bf16x8 b = *(const bf16x8*)(base + 8192 + (t * 16 + c) * 128 + kh * 64 + quad * 16);
        acc[t] = mfma32(a, b, acc[t]);
      }
    }
  };

  stage(0, 0);
#pragma unroll 1
  for (int s = 0; s < 6; ++s) {
    __syncthreads();
    if (s < 5) stage((s + 1) & 1, (s + 1) * 64);
    compute(s & 1);
  }

  int m0 = m0b + wave * 16;
#pragma unroll
  for (int t = 0; t < 4; ++t) {
    int o = n0 + t * 16 + c;
    float bv = proj_b[o];
#pragma unroll
    for (int r = 0; r < 4; ++r) {
      out[(long)(m0 + quad * 4 + r) * CC + o] = acc[t][r] + bv;
    }
  }
}

extern "C" void kernel_launch(void* const* d_in, const int* in_sizes, int n_in,
                              void* d_out, int out_size, void* d_ws, size_t ws_size,
                              hipStream_t stream) {
  const float* x = (const float*)d_in[0];
  const float* q_w = (const float*)d_in[1];
  const float* q_b = (const float*)d_in[2];
  const float* kv_w = (const float*)d_in[3];
  const float* kv_b = (const float*)d_in[4];
  const float* qe = (const float*)d_in[5];
  const float* temp = (const float*)d_in[6];
  const float* pos_bias = (const float*)d_in[7];
  const float* proj_w = (const float*)d_in[8];
  const float* proj_b = (const float*)d_in[9];
  float* out = (float*)d_out;

  char* ws = (char*)d_ws;
  unsigned short* xb = (unsigned short*)(ws + 0);          // 3,145,728 B
  unsigned short* qwb = (unsigned short*)(ws + 3145728);   //   294,912 B
  unsigned short* kvwb = (unsigned short*)(ws + 3440640);  //   589,824 B
  unsigned short* pwb = (unsigned short*)(ws + 4030464);   //   294,912 B
  unsigned short* Qs = (unsigned short*)(ws + 4325376);    // 3,145,728 B
  unsigned short* Kn = (unsigned short*)(ws + 7471104);    // 3,145,728 B
  unsigned short* VT = (unsigned short*)(ws + 10616832);   // 3,145,728 B
  unsigned short* ao = (unsigned short*)(ws + 13762560);   // 3,145,728 B -> 16.9 MB

  prep_kernel<<<8448, 256, 0, stream>>>(x, q_w, kv_w, proj_w, xb, qwb, kvwb, pwb);
  gemm_qkv_norm_kernel<<<dim3(64, NH), 256, 0, stream>>>(xb, qwb, kvwb, q_b, kv_b,
                                                         qe, temp, Qs, Kn, VT);
  attn_kernel<<<dim3(32, 24), 256, 0, stream>>>(Qs, Kn, VT, pos_bias, ao);
  proj_kernel<<<dim3(64, 6), 256, 0, stream>>>(ao, pwb, proj_b, out);
}